// Round 8
// baseline (367.209 us; speedup 1.0000x reference)
//
#include <hip/hip_runtime.h>

typedef unsigned short ushort_t;
typedef __attribute__((ext_vector_type(8))) short short8;
typedef __attribute__((ext_vector_type(4))) float f32x4;

// Problem constants
constexpr int NN = 100000;   // nodes
constexpr int D  = 128;      // feature dim
constexpr int NE = 1000000;  // edges per layer
constexpr int NP = 100000;   // pos/neg pairs

// Bucketed CSR build
constexpr int BK_SHIFT = 9;                      // 512 nodes per bucket
constexpr int NBK_L = (NN + 511) >> BK_SHIFT;    // 196 buckets per layer
constexpr int NBK   = 2 * NBK_L;                 // 392 total
constexpr int ACHUNK = 4096;                     // edges per block in A passes
constexpr int ABLOCKS = (2 * NE + ACHUNK - 1) / ACHUNK;   // 489

// prep_kernel block ranges
constexpr int PB_X   = 12500;            // x conversion
constexpr int PB_W   = PB_X + 256;       // W1,W2 transpose (128 each)
constexpr int PB_WP  = PB_W + 64;        // Wp1 transpose
constexpr int PB_CNT = PB_WP + ABLOCKS;  // bucket counting

// ---------------- bf16 helpers (manual RNE) --------------------------------
__device__ __forceinline__ float bf2f(ushort_t u) {
    union { unsigned int i; float f; } v; v.i = ((unsigned int)u) << 16; return v.f;
}
__device__ __forceinline__ ushort_t f2bf(float x) {
    union { float f; unsigned int i; } v; v.f = x;
    unsigned int r = v.i + 0x7fffu + ((v.i >> 16) & 1u);
    return (ushort_t)(r >> 16);
}
__device__ __forceinline__ void split2(float x, ushort_t& h, ushort_t& l) {
    h = f2bf(x);
    l = f2bf(x - bf2f(h));
}

// ---------------------------------------------------------------------------
// Fused prep + bucket count.
// [0,12500): x -> hi/lo bf16. [12500,12756): W1/W2 transpose+split.
// [12756,12820): Wp1. [12820,13309): per-block bucket histogram.
// ---------------------------------------------------------------------------
__global__ void __launch_bounds__(256) prep_kernel(
    const float* __restrict__ x,
    const float* __restrict__ Ws1, const float* __restrict__ Wn1,
    const float* __restrict__ Ws2, const float* __restrict__ Wn2,
    const float* __restrict__ Wp1,
    const int* __restrict__ ed1, const int* __restrict__ ed2,
    ushort_t* __restrict__ xh, ushort_t* __restrict__ xl,
    ushort_t* __restrict__ w1h, ushort_t* __restrict__ w1l,
    ushort_t* __restrict__ w2h, ushort_t* __restrict__ w2l,
    ushort_t* __restrict__ wph, ushort_t* __restrict__ wpl,
    int* __restrict__ btot)
{
    __shared__ int hist[NBK];
    int b = blockIdx.x;
    int t = threadIdx.x;
    if (b < PB_X) {
        int tid = b * 256 + t;
        float4 v = *reinterpret_cast<const float4*>(x + (size_t)tid * 4);
        ushort4 h4, l4;
        split2(v.x, h4.x, l4.x); split2(v.y, h4.y, l4.y);
        split2(v.z, h4.z, l4.z); split2(v.w, h4.w, l4.w);
        *reinterpret_cast<ushort4*>(xh + (size_t)tid * 4) = h4;
        *reinterpret_cast<ushort4*>(xl + (size_t)tid * 4) = l4;
    } else if (b < PB_W) {
        int layer2 = (b >= PB_X + 128);
        int tid = (b - (layer2 ? PB_X + 128 : PB_X)) * 256 + t;  // 32768
        int k = tid >> 7, n = tid & 127;
        const float* Ws = layer2 ? Ws2 : Ws1;
        const float* Wn = layer2 ? Wn2 : Wn1;
        ushort_t* Wth = layer2 ? w2h : w1h;
        ushort_t* Wtl = layer2 ? w2l : w1l;
        float v = (k < 128) ? Ws[k * 128 + n] : Wn[(k - 128) * 128 + n];
        ushort_t h, l; split2(v, h, l);
        Wth[n * 256 + k] = h; Wtl[n * 256 + k] = l;
    } else if (b < PB_WP) {
        int tid = (b - PB_W) * 256 + t;   // 16384
        int k = tid >> 7, n = tid & 127;
        float v = Wp1[k * 128 + n];
        ushort_t h, l; split2(v, h, l);
        wph[n * 128 + k] = h; wpl[n * 128 + k] = l;
    } else {
        // bucket counting
        for (int i = t; i < NBK; i += 256) hist[i] = 0;
        __syncthreads();
        int base = (b - PB_WP) * ACHUNK;
        for (int it = 0; it < ACHUNK / 256; ++it) {
            int e = base + it * 256 + t;
            if (e < 2 * NE) {
                int layer2 = (e >= NE);
                int d = layer2 ? ed2[e - NE] : ed1[e];
                atomicAdd(&hist[(layer2 ? NBK_L : 0) + (d >> BK_SHIFT)], 1);
            }
        }
        __syncthreads();
        for (int i = t; i < NBK; i += 256)
            if (hist[i]) atomicAdd(&btot[i], hist[i]);
    }
}

// ---------------------------------------------------------------------------
// Bucket scan: exclusive scan of 392 totals -> bbase[393], bcur[392]
// ---------------------------------------------------------------------------
__global__ void __launch_bounds__(512) bucket_scan_kernel(
    const int* __restrict__ btot, int* __restrict__ bbase, int* __restrict__ bcur)
{
    __shared__ int s[512];
    int t = threadIdx.x;
    int v = (t < NBK) ? btot[t] : 0;
    s[t] = v;
    __syncthreads();
    for (int off = 1; off < 512; off <<= 1) {
        int u = (t >= off) ? s[t - off] : 0;
        __syncthreads();
        s[t] += u;
        __syncthreads();
    }
    if (t < NBK) {
        int ex = s[t] - v;
        bbase[t] = ex;
        bcur[t] = ex;
        if (t == NBK - 1) bbase[NBK] = s[t];   // == 2*NE
    }
}

// ---------------------------------------------------------------------------
// Pass A2: scatter (src,dst) pairs into bucket-segmented pairbuf.
// ---------------------------------------------------------------------------
__global__ void __launch_bounds__(256) bucket_scatter_kernel(
    const int* __restrict__ es1, const int* __restrict__ ed1,
    const int* __restrict__ es2, const int* __restrict__ ed2,
    int* __restrict__ bcur, int2* __restrict__ pair)
{
    __shared__ int hist[NBK];
    __shared__ int rbase[NBK];
    __shared__ int cur[NBK];
    int t = threadIdx.x;
    for (int i = t; i < NBK; i += 256) hist[i] = 0;
    __syncthreads();
    int base = blockIdx.x * ACHUNK;
    for (int it = 0; it < ACHUNK / 256; ++it) {
        int e = base + it * 256 + t;
        if (e < 2 * NE) {
            int layer2 = (e >= NE);
            int d = layer2 ? ed2[e - NE] : ed1[e];
            atomicAdd(&hist[(layer2 ? NBK_L : 0) + (d >> BK_SHIFT)], 1);
        }
    }
    __syncthreads();
    for (int i = t; i < NBK; i += 256) {
        int h = hist[i];
        rbase[i] = h ? atomicAdd(&bcur[i], h) : 0;
        cur[i] = 0;
    }
    __syncthreads();
    for (int it = 0; it < ACHUNK / 256; ++it) {
        int e = base + it * 256 + t;
        if (e < 2 * NE) {
            int layer2 = (e >= NE);
            int s = layer2 ? es2[e - NE] : es1[e];
            int d = layer2 ? ed2[e - NE] : ed1[e];
            int bkt = (layer2 ? NBK_L : 0) + (d >> BK_SHIFT);
            int r = atomicAdd(&cur[bkt], 1);
            pair[(size_t)rbase[bkt] + r] = make_int2(s, d);
        }
    }
}

// ---------------------------------------------------------------------------
// Pass B: one block per bucket -> row_off + csr (L2-local scatter).
// ---------------------------------------------------------------------------
__global__ void __launch_bounds__(256) bucket_build_kernel(
    const int2* __restrict__ pair, const int* __restrict__ bbase,
    int* __restrict__ row_off, int* __restrict__ csr)
{
    __shared__ int cnt[512];
    __shared__ int sc[256];
    int b = blockIdx.x;
    int t = threadIdx.x;
    int layer2 = (b >= NBK_L);
    int n0 = (b - (layer2 ? NBK_L : 0)) << BK_SHIFT;
    int nodes = min(512, NN - n0);
    int gnode0 = n0 + (layer2 ? NN : 0);
    int e0 = bbase[b], e1 = bbase[b + 1];
    int m = e1 - e0;

    cnt[t] = 0; cnt[t + 256] = 0;
    __syncthreads();
    for (int j = t; j < m; j += 256)
        atomicAdd(&cnt[pair[(size_t)e0 + j].y - n0], 1);
    __syncthreads();

    int a0 = cnt[2 * t], a1 = cnt[2 * t + 1];
    sc[t] = a0 + a1;
    __syncthreads();
    for (int off = 1; off < 256; off <<= 1) {
        int u = (t >= off) ? sc[t - off] : 0;
        __syncthreads();
        sc[t] += u;
        __syncthreads();
    }
    int ex = sc[t] - (a0 + a1);
    cnt[2 * t] = ex;
    cnt[2 * t + 1] = ex + a0;
    __syncthreads();

    for (int i = t; i < nodes; i += 256)
        row_off[gnode0 + i] = e0 + cnt[i];
    if (b == NBK - 1 && t == 0) row_off[2 * NN] = 2 * NE;
    __syncthreads();

    for (int j = t; j < m; j += 256) {
        int2 p = pair[(size_t)e0 + j];
        int r = atomicAdd(&cnt[p.y - n0], 1);
        csr[(size_t)e0 + r] = p.x;
    }
}

// ---------------------------------------------------------------------------
// Gather-mean from FP32 features. Each 32-lane group handles TWO adjacent
// nodes with interleaved unroll-4 batches -> 8 independent row loads in
// flight per lane. Emits hi/lo bf16 means.
// ---------------------------------------------------------------------------
__global__ void __launch_bounds__(256) gather_mean_kernel(
    const float* __restrict__ feat,
    const int* __restrict__ row_off,
    const int* __restrict__ csr,
    ushort_t* __restrict__ mh, ushort_t* __restrict__ ml)
{
    int grp = (blockIdx.x * 256 + threadIdx.x) >> 5;   // 0..NN/2-1
    int lane = threadIdx.x & 31;
    int c = lane << 2;
    int g0 = grp * 2, g1 = g0 + 1;
    int j0 = row_off[g0], e0 = row_off[g0 + 1];
    int j1 = e0,          e1 = row_off[g1 + 1];        // ranges are contiguous
    int d0 = e0 - j0, d1 = e1 - j1;

    float4 a0a = make_float4(0.f, 0.f, 0.f, 0.f), a0b = a0a;
    float4 a1a = a0a, a1b = a0a;

    // phase 1: both nodes have >=4 left -> 8 loads in flight
    while (j0 + 4 <= e0 && j1 + 4 <= e1) {
        int s00 = csr[j0], s01 = csr[j0 + 1], s02 = csr[j0 + 2], s03 = csr[j0 + 3];
        int s10 = csr[j1], s11 = csr[j1 + 1], s12 = csr[j1 + 2], s13 = csr[j1 + 3];
        float4 v00 = *reinterpret_cast<const float4*>(feat + (size_t)s00 * D + c);
        float4 v01 = *reinterpret_cast<const float4*>(feat + (size_t)s01 * D + c);
        float4 v02 = *reinterpret_cast<const float4*>(feat + (size_t)s02 * D + c);
        float4 v03 = *reinterpret_cast<const float4*>(feat + (size_t)s03 * D + c);
        float4 v10 = *reinterpret_cast<const float4*>(feat + (size_t)s10 * D + c);
        float4 v11 = *reinterpret_cast<const float4*>(feat + (size_t)s11 * D + c);
        float4 v12 = *reinterpret_cast<const float4*>(feat + (size_t)s12 * D + c);
        float4 v13 = *reinterpret_cast<const float4*>(feat + (size_t)s13 * D + c);
        a0a.x += v00.x + v01.x; a0a.y += v00.y + v01.y;
        a0a.z += v00.z + v01.z; a0a.w += v00.w + v01.w;
        a0b.x += v02.x + v03.x; a0b.y += v02.y + v03.y;
        a0b.z += v02.z + v03.z; a0b.w += v02.w + v03.w;
        a1a.x += v10.x + v11.x; a1a.y += v10.y + v11.y;
        a1a.z += v10.z + v11.z; a1a.w += v10.w + v11.w;
        a1b.x += v12.x + v13.x; a1b.y += v12.y + v13.y;
        a1b.z += v12.z + v13.z; a1b.w += v12.w + v13.w;
        j0 += 4; j1 += 4;
    }
    // drain node 0
    while (j0 + 4 <= e0) {
        int s0 = csr[j0], s1 = csr[j0 + 1], s2 = csr[j0 + 2], s3 = csr[j0 + 3];
        float4 v0 = *reinterpret_cast<const float4*>(feat + (size_t)s0 * D + c);
        float4 v1 = *reinterpret_cast<const float4*>(feat + (size_t)s1 * D + c);
        float4 v2 = *reinterpret_cast<const float4*>(feat + (size_t)s2 * D + c);
        float4 v3 = *reinterpret_cast<const float4*>(feat + (size_t)s3 * D + c);
        a0a.x += v0.x + v1.x; a0a.y += v0.y + v1.y;
        a0a.z += v0.z + v1.z; a0a.w += v0.w + v1.w;
        a0b.x += v2.x + v3.x; a0b.y += v2.y + v3.y;
        a0b.z += v2.z + v3.z; a0b.w += v2.w + v3.w;
        j0 += 4;
    }
    // drain node 1
    while (j1 + 4 <= e1) {
        int s0 = csr[j1], s1 = csr[j1 + 1], s2 = csr[j1 + 2], s3 = csr[j1 + 3];
        float4 v0 = *reinterpret_cast<const float4*>(feat + (size_t)s0 * D + c);
        float4 v1 = *reinterpret_cast<const float4*>(feat + (size_t)s1 * D + c);
        float4 v2 = *reinterpret_cast<const float4*>(feat + (size_t)s2 * D + c);
        float4 v3 = *reinterpret_cast<const float4*>(feat + (size_t)s3 * D + c);
        a1a.x += v0.x + v1.x; a1a.y += v0.y + v1.y;
        a1a.z += v0.z + v1.z; a1a.w += v0.w + v1.w;
        a1b.x += v2.x + v3.x; a1b.y += v2.y + v3.y;
        a1b.z += v2.z + v3.z; a1b.w += v2.w + v3.w;
        j1 += 4;
    }
    // scalar tails (<=3 each), interleaved issue
    for (; j0 < e0; ++j0) {
        int s = csr[j0];
        float4 v = *reinterpret_cast<const float4*>(feat + (size_t)s * D + c);
        a0a.x += v.x; a0a.y += v.y; a0a.z += v.z; a0a.w += v.w;
    }
    for (; j1 < e1; ++j1) {
        int s = csr[j1];
        float4 v = *reinterpret_cast<const float4*>(feat + (size_t)s * D + c);
        a1a.x += v.x; a1a.y += v.y; a1a.z += v.z; a1a.w += v.w;
    }

    float r0 = 1.0f / fmaxf((float)d0, 1.0f);
    float r1 = 1.0f / fmaxf((float)d1, 1.0f);
    float m0x = (a0a.x + a0b.x) * r0, m0y = (a0a.y + a0b.y) * r0;
    float m0z = (a0a.z + a0b.z) * r0, m0w = (a0a.w + a0b.w) * r0;
    float m1x = (a1a.x + a1b.x) * r1, m1y = (a1a.y + a1b.y) * r1;
    float m1z = (a1a.z + a1b.z) * r1, m1w = (a1a.w + a1b.w) * r1;
    ushort4 h4, l4;
    split2(m0x, h4.x, l4.x); split2(m0y, h4.y, l4.y);
    split2(m0z, h4.z, l4.z); split2(m0w, h4.w, l4.w);
    *reinterpret_cast<ushort4*>(mh + (size_t)g0 * D + c) = h4;
    *reinterpret_cast<ushort4*>(ml + (size_t)g0 * D + c) = l4;
    split2(m1x, h4.x, l4.x); split2(m1y, h4.y, l4.y);
    split2(m1z, h4.z, l4.z); split2(m1w, h4.w, l4.w);
    *reinterpret_cast<ushort4*>(mh + (size_t)g1 * D + c) = h4;
    *reinterpret_cast<ushort4*>(ml + (size_t)g1 * D + c) = l4;
}

// ---------------------------------------------------------------------------
// MFMA split-bf16 SAGEConv GEMM, 128 rows/block, 8 waves.
// ---------------------------------------------------------------------------
template<bool RELU, bool WSPLIT, bool WF32>
__global__ void __launch_bounds__(512) mfma_sage_gemm(
    const ushort_t* __restrict__ Ah_self, const ushort_t* __restrict__ Al_self,
    const ushort_t* __restrict__ Ah_nei,  const ushort_t* __restrict__ Al_nei,
    const ushort_t* __restrict__ Wth, const ushort_t* __restrict__ Wtl,
    const float* __restrict__ bias,
    ushort_t* __restrict__ out_h, ushort_t* __restrict__ out_l,
    float* __restrict__ out_f)
{
    __shared__ short Bh[128 * 64];   // [n][64k] bf16, swizzled
    __shared__ short Bl[128 * 64];

    int t = threadIdx.x;
    int l = t & 63, w = t >> 6;      // 8 waves; wave = row-tile
    int lrow = l & 15, kg = l >> 4;
    int row0 = blockIdx.x * 128;
    int arow = row0 + w * 16 + lrow;
    int arow_c = min(arow, NN - 1);  // clamp for tail block loads

    f32x4 acc[8];
    for (int i = 0; i < 8; ++i) acc[i] = (f32x4)(0.f);

    for (int half = 0; half < 2; ++half) {
        const ushort_t* Ah = half ? Ah_nei : Ah_self;
        const ushort_t* Al = half ? Al_nei : Al_self;
        for (int kc2 = 0; kc2 < 2; ++kc2) {
            int kcat = half * 128 + kc2 * 64;
            __syncthreads();
            for (int i = 0; i < 2; ++i) {
                int s = t + i * 512;            // 1024 b128 slots per array
                int n = s >> 3;
                int k8 = (s & 7) * 8;
                short8 vh = *reinterpret_cast<const short8*>(Wth + n * 256 + kcat + k8);
                short8 vl = *reinterpret_cast<const short8*>(Wtl + n * 256 + kcat + k8);
                int db = n * 128 + ((k8 * 2) ^ ((n & 7) << 4));
                *reinterpret_cast<short8*>((char*)Bh + db) = vh;
                *reinterpret_cast<short8*>((char*)Bl + db) = vl;
            }
            __syncthreads();

            for (int ks = 0; ks < 2; ++ks) {
                int ka = kc2 * 64 + ks * 32 + kg * 8;
                short8 ah = *reinterpret_cast<const short8*>(Ah + (size_t)arow_c * D + ka);
                short8 al = *reinterpret_cast<const short8*>(Al + (size_t)arow_c * D + ka);
                int kb2 = (ks * 32 + kg * 8) * 2;
                for (int ct = 0; ct < 8; ++ct) {
                    int n = ct * 16 + lrow;
                    int db = n * 128 + (kb2 ^ ((n & 7) << 4));
                    short8 bh = *reinterpret_cast<const short8*>((char*)Bh + db);
                    short8 bl = *reinterpret_cast<const short8*>((char*)Bl + db);
                    acc[ct] = __builtin_amdgcn_mfma_f32_16x16x32_bf16(ah, bh, acc[ct], 0, 0, 0);
                    acc[ct] = __builtin_amdgcn_mfma_f32_16x16x32_bf16(ah, bl, acc[ct], 0, 0, 0);
                    acc[ct] = __builtin_amdgcn_mfma_f32_16x16x32_bf16(al, bh, acc[ct], 0, 0, 0);
                }
            }
        }
    }

    // epilogue: C/D layout col = lane&15, row = (lane>>4)*4 + j
    for (int ct = 0; ct < 8; ++ct) {
        int n = ct * 16 + lrow;
        float bv = bias[n];
        for (int j = 0; j < 4; ++j) {
            int r = row0 + w * 16 + kg * 4 + j;
            if (r >= NN) continue;
            float y = acc[ct][j] + bv;
            if (RELU) y = fmaxf(y, 0.f);
            if (WF32) out_f[(size_t)r * D + n] = y;
            if (WSPLIT) {
                ushort_t hh, ll; split2(y, hh, ll);
                out_h[(size_t)r * D + n] = hh;
                out_l[(size_t)r * D + n] = ll;
            }
        }
    }
}

// ---------------------------------------------------------------------------
// MFMA predictor, merged pos+neg: 64 pairs/block, 8 waves.
// ---------------------------------------------------------------------------
__global__ void __launch_bounds__(512) mfma_predictor(
    const float* __restrict__ H,
    const int* __restrict__ ps, const int* __restrict__ pd,
    const int* __restrict__ ns, const int* __restrict__ nd,
    const ushort_t* __restrict__ Wth, const ushort_t* __restrict__ Wtl,
    const float* __restrict__ bp1,
    const float* __restrict__ Wp2, const float* __restrict__ bp2,
    float* __restrict__ out)
{
    __shared__ short Zh[64 * 128];
    __shared__ short Zl[64 * 128];
    __shared__ short Bh[128 * 64];
    __shared__ short Bl[128 * 64];
    __shared__ float red[2][64];

    int t = threadIdx.x;
    int l = t & 63, w = t >> 6;
    int rt = w >> 1, ch = w & 1;
    int lrow = l & 15, kg = l >> 4;
    int row0 = blockIdx.x * 64;      // 3125 blocks x 64 pairs = 200000 exact

    for (int i = 0; i < 4; ++i) {
        int idx = t + i * 512;       // 2048 float4 slots
        int r = idx >> 5;
        int c4 = (idx & 31) << 2;
        int p = row0 + r;
        int s  = (p < NP) ? ps[p] : ns[p - NP];
        int d2 = (p < NP) ? pd[p] : nd[p - NP];
        float4 a = *reinterpret_cast<const float4*>(H + (size_t)s * D + c4);
        float4 b = *reinterpret_cast<const float4*>(H + (size_t)d2 * D + c4);
        float z0 = a.x * b.x, z1 = a.y * b.y, z2 = a.z * b.z, z3 = a.w * b.w;
        ushort4 h4, l4;
        split2(z0, h4.x, l4.x); split2(z1, h4.y, l4.y);
        split2(z2, h4.z, l4.z); split2(z3, h4.w, l4.w);
        int db = r * 256 + ((c4 * 2) ^ ((r & 7) << 4));
        *reinterpret_cast<ushort4*>((char*)Zh + db) = h4;
        *reinterpret_cast<ushort4*>((char*)Zl + db) = l4;
    }

    f32x4 acc[4];
    for (int i = 0; i < 4; ++i) acc[i] = (f32x4)(0.f);

    for (int kc = 0; kc < 2; ++kc) {
        __syncthreads();
        for (int i = 0; i < 2; ++i) {
            int s = t + i * 512;
            int n = s >> 3;
            int k8 = (s & 7) * 8;
            short8 vh = *reinterpret_cast<const short8*>(Wth + n * 128 + kc * 64 + k8);
            short8 vl = *reinterpret_cast<const short8*>(Wtl + n * 128 + kc * 64 + k8);
            int db = n * 128 + ((k8 * 2) ^ ((n & 7) << 4));
            *reinterpret_cast<short8*>((char*)Bh + db) = vh;
            *reinterpret_cast<short8*>((char*)Bl + db) = vl;
        }
        __syncthreads();

        for (int ks = 0; ks < 2; ++ks) {
            int zrow = rt * 16 + lrow;
            int kz2 = (kc * 64 + ks * 32 + kg * 8) * 2;
            int za = zrow * 256 + (kz2 ^ ((zrow & 7) << 4));
            short8 ah = *reinterpret_cast<const short8*>((char*)Zh + za);
            short8 al = *reinterpret_cast<const short8*>((char*)Zl + za);
            int kb2 = (ks * 32 + kg * 8) * 2;
            for (int ct = 0; ct < 4; ++ct) {
                int n = ch * 64 + ct * 16 + lrow;
                int db = n * 128 + (kb2 ^ ((n & 7) << 4));
                short8 bh = *reinterpret_cast<const short8*>((char*)Bh + db);
                short8 bl = *reinterpret_cast<const short8*>((char*)Bl + db);
                acc[ct] = __builtin_amdgcn_mfma_f32_16x16x32_bf16(ah, bh, acc[ct], 0, 0, 0);
                acc[ct] = __builtin_amdgcn_mfma_f32_16x16x32_bf16(ah, bl, acc[ct], 0, 0, 0);
                acc[ct] = __builtin_amdgcn_mfma_f32_16x16x32_bf16(al, bh, acc[ct], 0, 0, 0);
            }
        }
    }

    float partial[4] = {0.f, 0.f, 0.f, 0.f};
    for (int ct = 0; ct < 4; ++ct) {
        int n = ch * 64 + ct * 16 + lrow;
        float bv = bp1[n];
        float w2 = Wp2[n];
        for (int j = 0; j < 4; ++j) {
            float y = acc[ct][j] + bv;
            partial[j] += fmaxf(y, 0.f) * w2;
        }
    }
    for (int j = 0; j < 4; ++j)
        for (int off = 8; off >= 1; off >>= 1)
            partial[j] += __shfl_xor(partial[j], off);
    if (lrow == 0)
        for (int j = 0; j < 4; ++j)
            red[ch][rt * 16 + kg * 4 + j] = partial[j];
    __syncthreads();
    if (t < 64)
        out[row0 + t] = red[0][t] + red[1][t] + bp2[0];
}

// ---------------------------------------------------------------------------
extern "C" void kernel_launch(void* const* d_in, const int* in_sizes, int n_in,
                              void* d_out, int out_size, void* d_ws, size_t ws_size,
                              hipStream_t stream) {
    const float* x   = (const float*)d_in[0];
    const int*   es1 = (const int*)d_in[1];
    const int*   ed1 = (const int*)d_in[2];
    const int*   es2 = (const int*)d_in[3];
    const int*   ed2 = (const int*)d_in[4];
    const int*   ps  = (const int*)d_in[5];
    const int*   pd  = (const int*)d_in[6];
    const int*   ns  = (const int*)d_in[7];
    const int*   nd  = (const int*)d_in[8];
    const float* Ws1 = (const float*)d_in[9];
    const float* Wn1 = (const float*)d_in[10];
    const float* b1  = (const float*)d_in[11];
    const float* Ws2 = (const float*)d_in[12];
    const float* Wn2 = (const float*)d_in[13];
    const float* b2  = (const float*)d_in[14];
    const float* Wp1 = (const float*)d_in[15];
    const float* bp1 = (const float*)d_in[16];
    const float* Wp2 = (const float*)d_in[17];
    const float* bp2 = (const float*)d_in[18];
    float* out = (float*)d_out;

    char* ws = (char*)d_ws;
    size_t halfb = (size_t)NN * D * sizeof(ushort_t);  // 25.6 MB
    ushort_t* x_h    = (ushort_t*)(ws);                // -> h_h after layer-1 GEMM
    ushort_t* x_l    = (ushort_t*)(ws + halfb);        // -> h_l
    ushort_t* mean_h = (ushort_t*)(ws + 2 * halfb);
    ushort_t* mean_l = (ushort_t*)(ws + 3 * halfb);
    float*    hf     = (float*)(ws + 4 * halfb);       // fp32 h; later fp32 h2
    int2*     pair   = (int2*)hf;                      // pairbuf overlays hf
    char* wsp = ws + 4 * halfb + (size_t)NN * D * sizeof(float);
    ushort_t* w1t_h  = (ushort_t*)wsp;
    ushort_t* w1t_l  = w1t_h + 256 * 128;
    ushort_t* w2t_h  = w1t_l + 256 * 128;
    ushort_t* w2t_l  = w2t_h + 256 * 128;
    ushort_t* wpt_h  = w2t_l + 256 * 128;
    ushort_t* wpt_l  = wpt_h + 128 * 128;
    int* row_off = (int*)(wpt_l + 128 * 128 + 64);     // 2*NN + 1
    int* csr     = row_off + 2 * NN + 2;               // 2*NE
    int* btot    = csr + 2 * NE;                       // NBK
    int* bbase   = btot + NBK;                         // NBK + 1
    int* bcur    = bbase + NBK + 1;                    // NBK

    dim3 blk(256), blk512(512);
    int gatherBlocks = NN / 16;                  // 6250 (2 nodes per 32-lane grp)
    int gemmBlocks   = (NN + 127) / 128;         // 782
    int predBlocks   = 2 * NP / 64;              // 3125 exact

    // ---- Prep + bucketed CSR build (both layers) ----
    hipMemsetAsync(btot, 0, NBK * sizeof(int), stream);
    prep_kernel<<<PB_CNT, blk, 0, stream>>>(
        x, Ws1, Wn1, Ws2, Wn2, Wp1, ed1, ed2,
        x_h, x_l, w1t_h, w1t_l, w2t_h, w2t_l, wpt_h, wpt_l, btot);
    bucket_scan_kernel<<<1, 512, 0, stream>>>(btot, bbase, bcur);
    bucket_scatter_kernel<<<ABLOCKS, blk, 0, stream>>>(es1, ed1, es2, ed2, bcur, pair);
    bucket_build_kernel<<<NBK, blk, 0, stream>>>(pair, bbase, row_off, csr);

    // ---- Layer 1 ----
    gather_mean_kernel<<<gatherBlocks, blk, 0, stream>>>(x, row_off, csr, mean_h, mean_l);
    mfma_sage_gemm<true, true, true><<<gemmBlocks, blk512, 0, stream>>>(
        x_h, x_l, mean_h, mean_l, w1t_h, w1t_l, b1, x_h, x_l, hf);

    // ---- Layer 2 ----
    gather_mean_kernel<<<gatherBlocks, blk, 0, stream>>>(hf, row_off + NN, csr, mean_h, mean_l);
    mfma_sage_gemm<false, false, true><<<gemmBlocks, blk512, 0, stream>>>(
        x_h, x_l, mean_h, mean_l, w2t_h, w2t_l, b2, nullptr, nullptr, hf);

    // ---- Predictor (pos+neg merged) ----
    mfma_predictor<<<predBlocks, blk512, 0, stream>>>(
        hf, ps, pd, ns, nd, wpt_h, wpt_l, bp1, Wp2, bp2, out);
}